// Round 1
// baseline (33335.843 us; speedup 1.0000x reference)
//
#include <hip/hip_runtime.h>

// 2-layer GRU scan: L=512, B=256, D=H=512, 3H=1536.
// Persistent cooperative kernel: 256 blocks (1/CU) x 512 threads (8 waves).
// 8 groups of 32 CUs; group = bid&7 (XCD-aligned under round-robin dispatch),
// each group owns 32 batch rows for the entire scan.
// Per super-step s: layer0 computes h0[s], layer1 computes h1[s-1] (pipelined),
// one 32-block group barrier per step (agent-scope atomics in ws).
// Weights (Wh0,Wi1,Wh1 slices) staged in LDS as MFMA B-fragments (147 KB);
// Wi0 fragments streamed from global (ws, L2-resident); x fused in-loop.
// fp16 MFMA inputs, fp32 accumulate + fp32 recurrent state in registers.

#define LSEQ 512
#define TH3 1536

// ws layout (bytes); total need ~7.35 MB
#define WT_OFF   0                         // half WT[4][32][16][3][64][8] = 6291456 B
#define H0_OFF   6291456                   // half h0buf[8][2][32][512]    = 524288 B
#define H1_OFF   6815744                   // half h1buf[8][2][32][512]    = 524288 B
#define BAR_OFF  7340032                   // uint bar[8][64]              = 2048 B

typedef _Float16 f16x8 __attribute__((ext_vector_type(8)));
typedef float f32x4 __attribute__((ext_vector_type(4)));

__device__ __forceinline__ float sig_(float v) { return 1.0f / (1.0f + __expf(-v)); }
__device__ __forceinline__ float tanh_(float v) { return 2.0f / (1.0f + __expf(-2.0f * v)) - 1.0f; }

// Transpose all 4 weight matrices [512,1536] fp32 -> fp16 MFMA B-fragment layout in ws.
// Fragment layout per (w, cid): [kc 0..15][nt 0..2][lane 0..63][e 0..7] halves,
// where gate col = nt*512 + cid*16 + (lane&15), k = kc*32 + 8*(lane>>4) + e.
__global__ void prep_kernel(const float* __restrict__ Wh0, const float* __restrict__ Wi1,
                            const float* __restrict__ Wh1, const float* __restrict__ Wi0,
                            char* __restrict__ ws) {
  const int b = blockIdx.x;          // 2048 blocks
  const int w = b >> 9;              // 0:Wh0 1:Wi1 2:Wh1 3:Wi0
  const int k = b & 511;
  const float* src = (w == 0) ? Wh0 : (w == 1) ? Wi1 : (w == 2) ? Wh1 : Wi0;
  _Float16* dst = (_Float16*)(ws + WT_OFF);
  const int kc = k >> 5;
  const int lthi = ((k >> 3) & 3) << 4;
  const int e = k & 7;
  for (int col = threadIdx.x; col < TH3; col += 256) {
    float v = src[(size_t)k * TH3 + col];
    int nt = col >> 9, c = col & 511, cid = c >> 4, j = c & 15;
    size_t idx = (size_t)(w * 32 + cid) * 24576 + (size_t)((kc * 3 + nt) * 64 + lthi + j) * 8 + e;
    dst[idx] = (_Float16)v;
  }
  if (b == 0) {  // zero group barriers (replay-safe: done every call, stream-ordered)
    unsigned int* bar = (unsigned int*)(ws + BAR_OFF);
    for (int i = threadIdx.x; i < 512; i += 256) bar[i] = 0u;
  }
}

__device__ __forceinline__ void group_barrier(unsigned int* bar) {
  __syncthreads();
  if (threadIdx.x == 0) {
    unsigned int my = __hip_atomic_load(bar + 1, __ATOMIC_RELAXED, __HIP_MEMORY_SCOPE_AGENT);
    unsigned int prev = __hip_atomic_fetch_add(bar, 1u, __ATOMIC_ACQ_REL, __HIP_MEMORY_SCOPE_AGENT);
    if (prev == 31u) {
      __hip_atomic_store(bar, 0u, __ATOMIC_RELAXED, __HIP_MEMORY_SCOPE_AGENT);
      __hip_atomic_fetch_add(bar + 1, 1u, __ATOMIC_RELEASE, __HIP_MEMORY_SCOPE_AGENT);
    } else {
      while (__hip_atomic_load(bar + 1, __ATOMIC_ACQUIRE, __HIP_MEMORY_SCOPE_AGENT) == my) {
      }
    }
  }
  __syncthreads();
}

__global__ void __launch_bounds__(512, 2)
gru_kernel(const float* __restrict__ carry, const float* __restrict__ x,
           const float* __restrict__ bh0, const float* __restrict__ bh1,
           float* __restrict__ out, char* __restrict__ ws) {
  extern __shared__ char smem[];
  _Float16* Wlds = (_Float16*)smem;     // [3][16][3][64][8] fragments: Wh0,Wi1,Wh1 slices (147456 B)
  float* GH = (float*)(smem + 147456);  // [2 layer][3 nt][32 row][16 col] acc exchange (12288 B)

  const int bid = blockIdx.x;
  const int g = bid & 7, cid = bid >> 3;
  const int tid = threadIdx.x;
  const int wid = tid >> 6, lane = tid & 63;
  const int l16 = lane & 15, lhi = lane >> 4;
  const int mhalf = wid & 1, role = wid >> 1;  // 0:gh0 1:gi0 2:gi1 3:gh1

  _Float16* wt = (_Float16*)(ws + WT_OFF);
  _Float16* h0buf = (_Float16*)(ws + H0_OFF) + (size_t)g * 32768;  // [2 parity][32 row][512]
  _Float16* h1buf = (_Float16*)(ws + H1_OFF) + (size_t)g * 32768;
  unsigned int* bar = (unsigned int*)(ws + BAR_OFF) + g * 64;

  // Stage this CU's recurrent-weight fragments into LDS (straight vector copy).
  for (int w = 0; w < 3; ++w) {
    const f16x8* s8 = (const f16x8*)(wt + (size_t)(w * 32 + cid) * 24576);
    f16x8* d8 = (f16x8*)(Wlds + w * 24576);
    for (int i = tid; i < 3072; i += 512) d8[i] = s8[i];
  }

  const int hcol = cid * 16 + l16;
  const int rowq0 = mhalf * 16 + 4 * lhi;  // acc-tile rows rowq0+q (C/D layout, m89-verified)

  float bR = 0.f, bZ = 0.f, bN = 0.f;
  f32x4 hst = {0.f, 0.f, 0.f, 0.f};  // fp32 recurrent state (roles 1,2)
  if (role == 1 || role == 2) {
    const float* bh = (role == 1) ? bh0 : bh1;
    bR = bh[hcol]; bZ = bh[512 + hcol]; bN = bh[1024 + hcol];
    const int loff = (role == 1) ? 0 : 512;
    _Float16* hb = (role == 1) ? h0buf : h1buf;
#pragma unroll
    for (int q = 0; q < 4; ++q) {
      float h = carry[(size_t)(g * 32 + rowq0 + q) * 1024 + loff + hcol];
      hst[q] = h;
      hb[16384 + (rowq0 + q) * 512 + hcol] = (_Float16)h;  // prefill parity-1 (state at t=-1)
    }
  }
  __threadfence();
  group_barrier(bar);

  const f16x8* Wb0 = (const f16x8*)Wlds;                 // Wh0 frags (LDS)
  const f16x8* Wb1 = (const f16x8*)(Wlds + 24576);       // Wi1 frags (LDS)
  const f16x8* Wb2 = (const f16x8*)(Wlds + 2 * 24576);   // Wh1 frags (LDS)
  const f16x8* WbX = (const f16x8*)(wt + (size_t)(3 * 32 + cid) * 24576);  // Wi0 frags (global)

  for (int s = 0; s <= LSEQ; ++s) {
    const int pr = (s + 1) & 1;  // parity of state[s-1]
    const int pw = s & 1;        // parity of state[s] / state[s-2]
    f32x4 a0 = {0.f, 0.f, 0.f, 0.f}, a1 = {0.f, 0.f, 0.f, 0.f}, a2 = {0.f, 0.f, 0.f, 0.f};

    if (role == 0 && s < LSEQ) {            // gh0 = h0[s-1] @ Wh0
      const _Float16* Ap = h0buf + pr * 16384 + (mhalf * 16 + l16) * 512 + 8 * lhi;
#pragma unroll
      for (int kc = 0; kc < 16; ++kc) {
        f16x8 a = *(const f16x8*)(Ap + kc * 32);
        a0 = __builtin_amdgcn_mfma_f32_16x16x32_f16(a, Wb0[(kc * 3 + 0) * 64 + lane], a0, 0, 0, 0);
        a1 = __builtin_amdgcn_mfma_f32_16x16x32_f16(a, Wb0[(kc * 3 + 1) * 64 + lane], a1, 0, 0, 0);
        a2 = __builtin_amdgcn_mfma_f32_16x16x32_f16(a, Wb0[(kc * 3 + 2) * 64 + lane], a2, 0, 0, 0);
      }
#pragma unroll
      for (int q = 0; q < 4; ++q) {
        GH[(0 * 32 + rowq0 + q) * 16 + l16] = a0[q];
        GH[(1 * 32 + rowq0 + q) * 16 + l16] = a1[q];
        GH[(2 * 32 + rowq0 + q) * 16 + l16] = a2[q];
      }
    } else if (role == 3 && s >= 1) {       // gh1 = h1[s-2] @ Wh1
      const _Float16* Ap = h1buf + pw * 16384 + (mhalf * 16 + l16) * 512 + 8 * lhi;
#pragma unroll
      for (int kc = 0; kc < 16; ++kc) {
        f16x8 a = *(const f16x8*)(Ap + kc * 32);
        a0 = __builtin_amdgcn_mfma_f32_16x16x32_f16(a, Wb2[(kc * 3 + 0) * 64 + lane], a0, 0, 0, 0);
        a1 = __builtin_amdgcn_mfma_f32_16x16x32_f16(a, Wb2[(kc * 3 + 1) * 64 + lane], a1, 0, 0, 0);
        a2 = __builtin_amdgcn_mfma_f32_16x16x32_f16(a, Wb2[(kc * 3 + 2) * 64 + lane], a2, 0, 0, 0);
      }
#pragma unroll
      for (int q = 0; q < 4; ++q) {
        GH[((3 + 0) * 32 + rowq0 + q) * 16 + l16] = a0[q];
        GH[((3 + 1) * 32 + rowq0 + q) * 16 + l16] = a1[q];
        GH[((3 + 2) * 32 + rowq0 + q) * 16 + l16] = a2[q];
      }
    } else if (role == 1 && s < LSEQ) {     // gi0 = x[s] @ Wi0
      const float* xp = x + ((size_t)s * 256 + g * 32 + mhalf * 16 + l16) * 512 + 8 * lhi;
#pragma unroll
      for (int kc = 0; kc < 16; ++kc) {
        f32x4 xa = *(const f32x4*)(xp + kc * 32);
        f32x4 xb = *(const f32x4*)(xp + kc * 32 + 4);
        f16x8 a;
        a[0] = (_Float16)xa[0]; a[1] = (_Float16)xa[1]; a[2] = (_Float16)xa[2]; a[3] = (_Float16)xa[3];
        a[4] = (_Float16)xb[0]; a[5] = (_Float16)xb[1]; a[6] = (_Float16)xb[2]; a[7] = (_Float16)xb[3];
        a0 = __builtin_amdgcn_mfma_f32_16x16x32_f16(a, WbX[(kc * 3 + 0) * 64 + lane], a0, 0, 0, 0);
        a1 = __builtin_amdgcn_mfma_f32_16x16x32_f16(a, WbX[(kc * 3 + 1) * 64 + lane], a1, 0, 0, 0);
        a2 = __builtin_amdgcn_mfma_f32_16x16x32_f16(a, WbX[(kc * 3 + 2) * 64 + lane], a2, 0, 0, 0);
      }
    } else if (role == 2 && s >= 1) {       // gi1 = h0[s-1] @ Wi1
      const _Float16* Ap = h0buf + pr * 16384 + (mhalf * 16 + l16) * 512 + 8 * lhi;
#pragma unroll
      for (int kc = 0; kc < 16; ++kc) {
        f16x8 a = *(const f16x8*)(Ap + kc * 32);
        a0 = __builtin_amdgcn_mfma_f32_16x16x32_f16(a, Wb1[(kc * 3 + 0) * 64 + lane], a0, 0, 0, 0);
        a1 = __builtin_amdgcn_mfma_f32_16x16x32_f16(a, Wb1[(kc * 3 + 1) * 64 + lane], a1, 0, 0, 0);
        a2 = __builtin_amdgcn_mfma_f32_16x16x32_f16(a, Wb1[(kc * 3 + 2) * 64 + lane], a2, 0, 0, 0);
      }
    }
    __syncthreads();  // gh accs visible in LDS

    if (role == 1 && s < LSEQ) {            // layer-0 epilogue -> h0[s]
#pragma unroll
      for (int q = 0; q < 4; ++q) {
        const int row = rowq0 + q;
        float r = sig_(a0[q] + GH[(0 * 32 + row) * 16 + l16] + bR);
        float z = sig_(a1[q] + GH[(1 * 32 + row) * 16 + l16] + bZ);
        float n = tanh_(a2[q] + r * (GH[(2 * 32 + row) * 16 + l16] + bN));
        float h = (1.0f - z) * n + z * hst[q];
        hst[q] = h;
        h0buf[pw * 16384 + row * 512 + hcol] = (_Float16)h;
        if (s == LSEQ - 1) out[(size_t)(g * 32 + row) * 1024 + hcol] = h;  // carry h0
      }
    } else if (role == 2 && s >= 1) {       // layer-1 epilogue -> h1[s-1]
#pragma unroll
      for (int q = 0; q < 4; ++q) {
        const int row = rowq0 + q;
        float r = sig_(a0[q] + GH[((3 + 0) * 32 + row) * 16 + l16] + bR);
        float z = sig_(a1[q] + GH[((3 + 1) * 32 + row) * 16 + l16] + bZ);
        float n = tanh_(a2[q] + r * (GH[((3 + 2) * 32 + row) * 16 + l16] + bN));
        float h = (1.0f - z) * n + z * hst[q];
        hst[q] = h;
        h1buf[pr * 16384 + row * 512 + hcol] = (_Float16)h;
        out[(size_t)262144 + ((size_t)(s - 1) * 256 + g * 32 + row) * 512 + hcol] = h;  // y[s-1]
        if (s == LSEQ) out[(size_t)(g * 32 + row) * 1024 + 512 + hcol] = h;             // carry h1
      }
    }
    __threadfence();
    group_barrier(bar);
  }
}

extern "C" void kernel_launch(void* const* d_in, const int* in_sizes, int n_in,
                              void* d_out, int out_size, void* d_ws, size_t ws_size,
                              hipStream_t stream) {
  const float* carry = (const float*)d_in[0];
  const float* x     = (const float*)d_in[1];
  const float* Wi0   = (const float*)d_in[2];
  const float* Wh0   = (const float*)d_in[3];
  const float* bh0   = (const float*)d_in[4];
  const float* Wi1   = (const float*)d_in[5];
  const float* Wh1   = (const float*)d_in[6];
  const float* bh1   = (const float*)d_in[7];
  float* out = (float*)d_out;
  char* ws = (char*)d_ws;

  prep_kernel<<<2048, 256, 0, stream>>>(Wh0, Wi1, Wh1, Wi0, ws);

  (void)hipFuncSetAttribute(reinterpret_cast<const void*>(gru_kernel),
                            hipFuncAttributeMaxDynamicSharedMemorySize, 159744);

  void* args[] = {(void*)&carry, (void*)&x, (void*)&bh0, (void*)&bh1, (void*)&out, (void*)&ws};
  (void)hipLaunchCooperativeKernel(reinterpret_cast<void*>(gru_kernel),
                                   dim3(256), dim3(512), args, 159744, stream);
}

// Round 2
// 9716.517 us; speedup vs baseline: 3.4308x; 3.4308x over previous
//
#include <hip/hip_runtime.h>

// 2-layer GRU scan: L=512, B=256, D=H=512, 3H=1536.
// Persistent cooperative kernel: 256 blocks (1/CU) x 512 threads (8 waves).
// 8 groups of 32 CUs; each group owns 32 batch rows for the entire scan.
// Per super-step s: layer0 computes h0[s], layer1 computes h1[s-1] (pipelined),
// one 32-block group barrier per step.
// R2 change: NO cache-wide fences in the step loop. Cross-block h-state goes
// through the Infinity Cache with per-access coherence (sc0 sc1 bypass
// loads/stores); barrier uses RELAXED agent atomics only; ordering via
// s_waitcnt vmcnt(0) (+ sched_barrier to stop MFMA hoisting, rule #18).

#define LSEQ 512
#define TH3 1536

// ws layout (bytes); total need ~7.35 MB
#define WT_OFF   0                         // half WT[4][32][16][3][64][8] = 6291456 B
#define H0_OFF   6291456                   // half h0buf[8][2][32][512]    = 524288 B
#define H1_OFF   6815744                   // half h1buf[8][2][32][512]    = 524288 B
#define BAR_OFF  7340032                   // uint bar[8][64]              = 2048 B

typedef _Float16 f16x8 __attribute__((ext_vector_type(8)));
typedef float f32x4 __attribute__((ext_vector_type(4)));

__device__ __forceinline__ float sig_(float v) { return 1.0f / (1.0f + __expf(-v)); }
__device__ __forceinline__ float tanh_(float v) { return 2.0f / (1.0f + __expf(-2.0f * v)) - 1.0f; }

// 16B load that bypasses L1/L2 (reads coherence point = Infinity Cache).
// Result NOT ready until s_waitcnt vmcnt(0)!
__device__ __forceinline__ f32x4 load16_bypass(const void* p) {
  f32x4 r;
  asm volatile("global_load_dwordx4 %0, %1, off sc0 sc1" : "=v"(r) : "v"(p));
  return r;
}
// 2B store written through to the coherence point.
__device__ __forceinline__ void store2_bypass(_Float16* p, _Float16 v) {
  asm volatile("global_store_short %0, %1, off sc0 sc1" :: "v"(p), "v"(v) : "memory");
}

// Transpose all 4 weight matrices [512,1536] fp32 -> fp16 MFMA B-fragment layout in ws.
// Fragment layout per (w, cid): [kc 0..15][nt 0..2][lane 0..63][e 0..7] halves,
// where gate col = nt*512 + cid*16 + (lane&15), k = kc*32 + 8*(lane>>4) + e.
__global__ void prep_kernel(const float* __restrict__ Wh0, const float* __restrict__ Wi1,
                            const float* __restrict__ Wh1, const float* __restrict__ Wi0,
                            char* __restrict__ ws) {
  const int b = blockIdx.x;          // 2048 blocks
  const int w = b >> 9;              // 0:Wh0 1:Wi1 2:Wh1 3:Wi0
  const int k = b & 511;
  const float* src = (w == 0) ? Wh0 : (w == 1) ? Wi1 : (w == 2) ? Wh1 : Wi0;
  _Float16* dst = (_Float16*)(ws + WT_OFF);
  const int kc = k >> 5;
  const int lthi = ((k >> 3) & 3) << 4;
  const int e = k & 7;
  for (int col = threadIdx.x; col < TH3; col += 256) {
    float v = src[(size_t)k * TH3 + col];
    int nt = col >> 9, c = col & 511, cid = c >> 4, j = c & 15;
    size_t idx = (size_t)(w * 32 + cid) * 24576 + (size_t)((kc * 3 + nt) * 64 + lthi + j) * 8 + e;
    dst[idx] = (_Float16)v;
  }
  if (b == 0) {  // zero group barriers (replay-safe: done every call, stream-ordered)
    unsigned int* bar = (unsigned int*)(ws + BAR_OFF);
    for (int i = threadIdx.x; i < 512; i += 256) bar[i] = 0u;
  }
}

// Group barrier: RELAXED agent atomics only — no buffer_wbl2/buffer_inv.
// Producer-side store completion is guaranteed by the vmcnt(0) drain the
// compiler emits before s_barrier inside __syncthreads().
__device__ __forceinline__ void group_barrier(unsigned int* bar) {
  __syncthreads();
  if (threadIdx.x == 0) {
    unsigned int my = __hip_atomic_load(bar + 1, __ATOMIC_RELAXED, __HIP_MEMORY_SCOPE_AGENT);
    unsigned int prev = __hip_atomic_fetch_add(bar, 1u, __ATOMIC_RELAXED, __HIP_MEMORY_SCOPE_AGENT);
    if (prev == 31u) {
      __hip_atomic_store(bar, 0u, __ATOMIC_RELAXED, __HIP_MEMORY_SCOPE_AGENT);
      __hip_atomic_fetch_add(bar + 1, 1u, __ATOMIC_RELAXED, __HIP_MEMORY_SCOPE_AGENT);
    } else {
      while (__hip_atomic_load(bar + 1, __ATOMIC_RELAXED, __HIP_MEMORY_SCOPE_AGENT) == my) {
      }
    }
  }
  __syncthreads();
}

__global__ void __launch_bounds__(512, 2)
gru_kernel(const float* __restrict__ carry, const float* __restrict__ x,
           const float* __restrict__ bh0, const float* __restrict__ bh1,
           float* __restrict__ out, char* __restrict__ ws) {
  extern __shared__ char smem[];
  _Float16* Wlds = (_Float16*)smem;     // [3][16][3][64][8] fragments: Wh0,Wi1,Wh1 slices (147456 B)
  float* GH = (float*)(smem + 147456);  // [2 layer][3 nt][32 row][16 col] acc exchange (12288 B)

  const int bid = blockIdx.x;
  const int g = bid & 7, cid = bid >> 3;
  const int tid = threadIdx.x;
  const int wid = tid >> 6, lane = tid & 63;
  const int l16 = lane & 15, lhi = lane >> 4;
  const int mhalf = wid & 1, role = wid >> 1;  // 0:gh0 1:gi0 2:gi1 3:gh1

  _Float16* wt = (_Float16*)(ws + WT_OFF);
  _Float16* h0buf = (_Float16*)(ws + H0_OFF) + (size_t)g * 32768;  // [2 parity][32 row][512]
  _Float16* h1buf = (_Float16*)(ws + H1_OFF) + (size_t)g * 32768;
  unsigned int* bar = (unsigned int*)(ws + BAR_OFF) + g * 64;

  // Stage this CU's recurrent-weight fragments into LDS (straight vector copy).
  for (int w = 0; w < 3; ++w) {
    const f16x8* s8 = (const f16x8*)(wt + (size_t)(w * 32 + cid) * 24576);
    f16x8* d8 = (f16x8*)(Wlds + w * 24576);
    for (int i = tid; i < 3072; i += 512) d8[i] = s8[i];
  }

  const int hcol = cid * 16 + l16;
  const int rowq0 = mhalf * 16 + 4 * lhi;  // acc-tile rows rowq0+q (C/D layout, m89-verified)

  float bR = 0.f, bZ = 0.f, bN = 0.f;
  f32x4 hst = {0.f, 0.f, 0.f, 0.f};  // fp32 recurrent state (roles 1,2)
  if (role == 1 || role == 2) {
    const float* bh = (role == 1) ? bh0 : bh1;
    bR = bh[hcol]; bZ = bh[512 + hcol]; bN = bh[1024 + hcol];
    const int loff = (role == 1) ? 0 : 512;
    _Float16* hb = (role == 1) ? h0buf : h1buf;
#pragma unroll
    for (int q = 0; q < 4; ++q) {
      float h = carry[(size_t)(g * 32 + rowq0 + q) * 1024 + loff + hcol];
      hst[q] = h;
      store2_bypass(&hb[16384 + (rowq0 + q) * 512 + hcol], (_Float16)h);  // prefill parity-1
    }
    asm volatile("s_waitcnt vmcnt(0)" ::: "memory");
  }
  group_barrier(bar);

  const f16x8* Wb0 = (const f16x8*)Wlds;                 // Wh0 frags (LDS)
  const f16x8* Wb1 = (const f16x8*)(Wlds + 24576);       // Wi1 frags (LDS)
  const f16x8* Wb2 = (const f16x8*)(Wlds + 2 * 24576);   // Wh1 frags (LDS)
  const f16x8* WbX = (const f16x8*)(wt + (size_t)(3 * 32 + cid) * 24576);  // Wi0 frags (global, L2-resident)

  for (int s = 0; s <= LSEQ; ++s) {
    const int pr = (s + 1) & 1;  // parity of state[s-1]
    const int pw = s & 1;        // parity of state[s] / state[s-2]
    f32x4 a0 = {0.f, 0.f, 0.f, 0.f}, a1 = {0.f, 0.f, 0.f, 0.f}, a2 = {0.f, 0.f, 0.f, 0.f};

    if (role == 0 && s < LSEQ) {            // gh0 = h0[s-1] @ Wh0
      const _Float16* Ap = h0buf + pr * 16384 + (mhalf * 16 + l16) * 512 + 8 * lhi;
      f16x8 afr[16];
#pragma unroll
      for (int kc = 0; kc < 16; ++kc) afr[kc] = __builtin_bit_cast(f16x8, load16_bypass(Ap + kc * 32));
      asm volatile("s_waitcnt vmcnt(0)" ::: "memory");
      __builtin_amdgcn_sched_barrier(0);
#pragma unroll
      for (int kc = 0; kc < 16; ++kc) {
        a0 = __builtin_amdgcn_mfma_f32_16x16x32_f16(afr[kc], Wb0[(kc * 3 + 0) * 64 + lane], a0, 0, 0, 0);
        a1 = __builtin_amdgcn_mfma_f32_16x16x32_f16(afr[kc], Wb0[(kc * 3 + 1) * 64 + lane], a1, 0, 0, 0);
        a2 = __builtin_amdgcn_mfma_f32_16x16x32_f16(afr[kc], Wb0[(kc * 3 + 2) * 64 + lane], a2, 0, 0, 0);
      }
#pragma unroll
      for (int q = 0; q < 4; ++q) {
        GH[(0 * 32 + rowq0 + q) * 16 + l16] = a0[q];
        GH[(1 * 32 + rowq0 + q) * 16 + l16] = a1[q];
        GH[(2 * 32 + rowq0 + q) * 16 + l16] = a2[q];
      }
    } else if (role == 3 && s >= 1) {       // gh1 = h1[s-2] @ Wh1
      const _Float16* Ap = h1buf + pw * 16384 + (mhalf * 16 + l16) * 512 + 8 * lhi;
      f16x8 afr[16];
#pragma unroll
      for (int kc = 0; kc < 16; ++kc) afr[kc] = __builtin_bit_cast(f16x8, load16_bypass(Ap + kc * 32));
      asm volatile("s_waitcnt vmcnt(0)" ::: "memory");
      __builtin_amdgcn_sched_barrier(0);
#pragma unroll
      for (int kc = 0; kc < 16; ++kc) {
        a0 = __builtin_amdgcn_mfma_f32_16x16x32_f16(afr[kc], Wb2[(kc * 3 + 0) * 64 + lane], a0, 0, 0, 0);
        a1 = __builtin_amdgcn_mfma_f32_16x16x32_f16(afr[kc], Wb2[(kc * 3 + 1) * 64 + lane], a1, 0, 0, 0);
        a2 = __builtin_amdgcn_mfma_f32_16x16x32_f16(afr[kc], Wb2[(kc * 3 + 2) * 64 + lane], a2, 0, 0, 0);
      }
#pragma unroll
      for (int q = 0; q < 4; ++q) {
        GH[((3 + 0) * 32 + rowq0 + q) * 16 + l16] = a0[q];
        GH[((3 + 1) * 32 + rowq0 + q) * 16 + l16] = a1[q];
        GH[((3 + 2) * 32 + rowq0 + q) * 16 + l16] = a2[q];
      }
    } else if (role == 1 && s < LSEQ) {     // gi0 = x[s] @ Wi0
      const float* xp = x + ((size_t)s * 256 + g * 32 + mhalf * 16 + l16) * 512 + 8 * lhi;
#pragma unroll
      for (int kc = 0; kc < 16; ++kc) {
        f32x4 xa = *(const f32x4*)(xp + kc * 32);
        f32x4 xb = *(const f32x4*)(xp + kc * 32 + 4);
        f16x8 a;
        a[0] = (_Float16)xa[0]; a[1] = (_Float16)xa[1]; a[2] = (_Float16)xa[2]; a[3] = (_Float16)xa[3];
        a[4] = (_Float16)xb[0]; a[5] = (_Float16)xb[1]; a[6] = (_Float16)xb[2]; a[7] = (_Float16)xb[3];
        a0 = __builtin_amdgcn_mfma_f32_16x16x32_f16(a, WbX[(kc * 3 + 0) * 64 + lane], a0, 0, 0, 0);
        a1 = __builtin_amdgcn_mfma_f32_16x16x32_f16(a, WbX[(kc * 3 + 1) * 64 + lane], a1, 0, 0, 0);
        a2 = __builtin_amdgcn_mfma_f32_16x16x32_f16(a, WbX[(kc * 3 + 2) * 64 + lane], a2, 0, 0, 0);
      }
    } else if (role == 2 && s >= 1) {       // gi1 = h0[s-1] @ Wi1
      const _Float16* Ap = h0buf + pr * 16384 + (mhalf * 16 + l16) * 512 + 8 * lhi;
      f16x8 afr[16];
#pragma unroll
      for (int kc = 0; kc < 16; ++kc) afr[kc] = __builtin_bit_cast(f16x8, load16_bypass(Ap + kc * 32));
      asm volatile("s_waitcnt vmcnt(0)" ::: "memory");
      __builtin_amdgcn_sched_barrier(0);
#pragma unroll
      for (int kc = 0; kc < 16; ++kc) {
        a0 = __builtin_amdgcn_mfma_f32_16x16x32_f16(afr[kc], Wb1[(kc * 3 + 0) * 64 + lane], a0, 0, 0, 0);
        a1 = __builtin_amdgcn_mfma_f32_16x16x32_f16(afr[kc], Wb1[(kc * 3 + 1) * 64 + lane], a1, 0, 0, 0);
        a2 = __builtin_amdgcn_mfma_f32_16x16x32_f16(afr[kc], Wb1[(kc * 3 + 2) * 64 + lane], a2, 0, 0, 0);
      }
    }
    __syncthreads();  // gh accs visible in LDS

    if (role == 1 && s < LSEQ) {            // layer-0 epilogue -> h0[s]
#pragma unroll
      for (int q = 0; q < 4; ++q) {
        const int row = rowq0 + q;
        float r = sig_(a0[q] + GH[(0 * 32 + row) * 16 + l16] + bR);
        float z = sig_(a1[q] + GH[(1 * 32 + row) * 16 + l16] + bZ);
        float n = tanh_(a2[q] + r * (GH[(2 * 32 + row) * 16 + l16] + bN));
        float h = (1.0f - z) * n + z * hst[q];
        hst[q] = h;
        store2_bypass(&h0buf[pw * 16384 + row * 512 + hcol], (_Float16)h);
        if (s == LSEQ - 1) out[(size_t)(g * 32 + row) * 1024 + hcol] = h;  // carry h0
      }
      asm volatile("s_waitcnt vmcnt(0)" ::: "memory");
    } else if (role == 2 && s >= 1) {       // layer-1 epilogue -> h1[s-1]
#pragma unroll
      for (int q = 0; q < 4; ++q) {
        const int row = rowq0 + q;
        float r = sig_(a0[q] + GH[((3 + 0) * 32 + row) * 16 + l16] + bR);
        float z = sig_(a1[q] + GH[((3 + 1) * 32 + row) * 16 + l16] + bZ);
        float n = tanh_(a2[q] + r * (GH[((3 + 2) * 32 + row) * 16 + l16] + bN));
        float h = (1.0f - z) * n + z * hst[q];
        hst[q] = h;
        store2_bypass(&h1buf[pr * 16384 + row * 512 + hcol], (_Float16)h);
        out[(size_t)262144 + ((size_t)(s - 1) * 256 + g * 32 + row) * 512 + hcol] = h;  // y[s-1]
        if (s == LSEQ) out[(size_t)(g * 32 + row) * 1024 + 512 + hcol] = h;             // carry h1
      }
      asm volatile("s_waitcnt vmcnt(0)" ::: "memory");
    }
    group_barrier(bar);
  }
}

extern "C" void kernel_launch(void* const* d_in, const int* in_sizes, int n_in,
                              void* d_out, int out_size, void* d_ws, size_t ws_size,
                              hipStream_t stream) {
  const float* carry = (const float*)d_in[0];
  const float* x     = (const float*)d_in[1];
  const float* Wi0   = (const float*)d_in[2];
  const float* Wh0   = (const float*)d_in[3];
  const float* bh0   = (const float*)d_in[4];
  const float* Wi1   = (const float*)d_in[5];
  const float* Wh1   = (const float*)d_in[6];
  const float* bh1   = (const float*)d_in[7];
  float* out = (float*)d_out;
  char* ws = (char*)d_ws;

  prep_kernel<<<2048, 256, 0, stream>>>(Wh0, Wi1, Wh1, Wi0, ws);

  (void)hipFuncSetAttribute(reinterpret_cast<const void*>(gru_kernel),
                            hipFuncAttributeMaxDynamicSharedMemorySize, 159744);

  void* args[] = {(void*)&carry, (void*)&x, (void*)&bh0, (void*)&bh1, (void*)&out, (void*)&ws};
  (void)hipLaunchCooperativeKernel(reinterpret_cast<void*>(gru_kernel),
                                   dim3(256), dim3(512), args, 159744, stream);
}

// Round 4
// 8616.267 us; speedup vs baseline: 3.8689x; 1.1277x over previous
//
#include <hip/hip_runtime.h>

// 2-layer GRU scan: L=512, B=256, D=H=512, 3H=1536.
// Persistent cooperative kernel: 256 blocks (1/CU, LDS-pinned) x 512 threads.
// Groups of 32 blocks own 32 batch rows for the whole scan; layer0 step s and
// layer1 step s-1 run concurrently; ONE group barrier per super-step.
//
// R4: - Barrier = monotonic counter with RELAXED-AGENT atomics (execute at
//       IF$, polls bypass L2) — fixes R3's deadlock (sc0 polls cached a stale
//       L2 line while plain atomics executed at IF$; m20).
//     - h-state exchange stays XCD-L2-local (sc0 stores/loads) WHEN runtime
//       discovery (HW_REG_XCC_ID + rank atomics) verifies all 8 XCC groups
//       have exactly 32 blocks; otherwise ALL blocks fall back to bid-groups
//       with IF$ (sc0 sc1) exchange = R2 semantics (proven correct). The
//       verification uses a one-time global 256-block IF$ barrier, so no
//       configuration can deadlock (G16).

#define LSEQ 512
#define TH3 1536

// ws layout (bytes); total need ~7.35 MB
#define WT_OFF   0                         // half WT[4][32][16][3][64][8] = 6291456 B
#define H0_OFF   6291456                   // half h0buf[8][2][32][512]    = 524288 B
#define H1_OFF   6815744                   // half h1buf[8][2][32][512]    = 524288 B
#define BAR_OFF  7340032                   // uint bar[8][64]              = 2048 B
#define RANK_OFF 7342080                   // uint rank[8][64]             = 2048 B
#define GBAR_OFF 7344128                   // uint gbar[64]                = 256 B
#define BAD_OFF  7344384                   // uint bad[64]                 = 256 B

typedef _Float16 f16x8 __attribute__((ext_vector_type(8)));
typedef float f32x4 __attribute__((ext_vector_type(4)));

__device__ __forceinline__ float sig_(float v) { return 1.0f / (1.0f + __expf(-v)); }
__device__ __forceinline__ float tanh_(float v) { return 2.0f / (1.0f + __expf(-2.0f * v)) - 1.0f; }

// h-state access. FAST: producers+consumers share the physical XCD L2 ->
// sc0 (bypass L1, hit local L2). SLOW: groups may span XCDs -> sc0 sc1
// (bypass to IF$ coherence point; R2-proven).
template <bool FAST>
__device__ __forceinline__ f32x4 load16h(const void* p) {
  f32x4 r;
  if (FAST) asm volatile("global_load_dwordx4 %0, %1, off sc0" : "=v"(r) : "v"(p));
  else      asm volatile("global_load_dwordx4 %0, %1, off sc0 sc1" : "=v"(r) : "v"(p));
  return r;  // NOT ready until s_waitcnt vmcnt(0)
}
template <bool FAST>
__device__ __forceinline__ void store2h(_Float16* p, _Float16 v) {
  if (FAST) asm volatile("global_store_short %0, %1, off sc0" :: "v"(p), "v"(v) : "memory");
  else      asm volatile("global_store_short %0, %1, off sc0 sc1" :: "v"(p), "v"(v) : "memory");
}

// Transpose all 4 weight matrices [512,1536] fp32 -> fp16 MFMA B-fragment layout in ws.
// Fragment layout per (w, cid): [kc 0..15][nt 0..2][lane 0..63][e 0..7] halves,
// where gate col = nt*512 + cid*16 + (lane&15), k = kc*32 + 8*(lane>>4) + e.
__global__ void prep_kernel(const float* __restrict__ Wh0, const float* __restrict__ Wi1,
                            const float* __restrict__ Wh1, const float* __restrict__ Wi0,
                            char* __restrict__ ws) {
  const int b = blockIdx.x;          // 2048 blocks
  const int w = b >> 9;              // 0:Wh0 1:Wi1 2:Wh1 3:Wi0
  const int k = b & 511;
  const float* src = (w == 0) ? Wh0 : (w == 1) ? Wi1 : (w == 2) ? Wh1 : Wi0;
  _Float16* dst = (_Float16*)(ws + WT_OFF);
  const int kc = k >> 5;
  const int lthi = ((k >> 3) & 3) << 4;
  const int e = k & 7;
  for (int col = threadIdx.x; col < TH3; col += 256) {
    float v = src[(size_t)k * TH3 + col];
    int nt = col >> 9, c = col & 511, cid = c >> 4, j = c & 15;
    size_t idx = (size_t)(w * 32 + cid) * 24576 + (size_t)((kc * 3 + nt) * 64 + lthi + j) * 8 + e;
    dst[idx] = (_Float16)v;
  }
  if (b == 0) {  // zero all sync counters (every call; visible to gru via
                 // end-of-dispatch L2 writeback + start-of-dispatch invalidate)
    unsigned int* z = (unsigned int*)(ws + BAR_OFF);
    for (int i = threadIdx.x; i < 1152; i += 256) z[i] = 0u;
  }
}

// Monotonic group barrier at IF$: RELAXED-AGENT add + poll (both bypass the
// non-coherent XCD L2s). Producer stores are drained by the vmcnt(0) the
// compiler emits before s_barrier in __syncthreads().
__device__ __forceinline__ void group_barrier(unsigned int* barp, unsigned int target, int tid) {
  __syncthreads();
  if (tid == 0) {
    __hip_atomic_fetch_add(barp, 1u, __ATOMIC_RELAXED, __HIP_MEMORY_SCOPE_AGENT);
    while (__hip_atomic_load(barp, __ATOMIC_RELAXED, __HIP_MEMORY_SCOPE_AGENT) < target) {}
  }
  __syncthreads();
}

template <bool FAST>
__device__ __forceinline__ void run_scan(int g, int cid, const float* carry, const float* x,
                                         const float* bh0, const float* bh1, float* out,
                                         char* ws, _Float16* Wlds, float* GH) {
  const int tid = threadIdx.x;
  const int wid = tid >> 6, lane = tid & 63;
  const int l16 = lane & 15, lhi = lane >> 4;
  const int mhalf = wid & 1, role = wid >> 1;  // 0:gh0 1:gi0 2:gi1 3:gh1

  _Float16* wt = (_Float16*)(ws + WT_OFF);
  _Float16* h0buf = (_Float16*)(ws + H0_OFF) + (size_t)g * 32768;  // [2 parity][32 row][512]
  _Float16* h1buf = (_Float16*)(ws + H1_OFF) + (size_t)g * 32768;
  unsigned int* barp = (unsigned int*)(ws + BAR_OFF) + g * 64;
  unsigned int phase = 0;

  const int hcol = cid * 16 + l16;
  const int rowq0 = mhalf * 16 + 4 * lhi;  // acc-tile rows rowq0+q (C/D layout, m89-verified)

  float bR = 0.f, bZ = 0.f, bN = 0.f;
  f32x4 hst = {0.f, 0.f, 0.f, 0.f};  // fp32 recurrent state (roles 1,2)
  if (role == 1 || role == 2) {
    const float* bh = (role == 1) ? bh0 : bh1;
    bR = bh[hcol]; bZ = bh[512 + hcol]; bN = bh[1024 + hcol];
    const int loff = (role == 1) ? 0 : 512;
    _Float16* hb = (role == 1) ? h0buf : h1buf;
#pragma unroll
    for (int q = 0; q < 4; ++q) {
      float h = carry[(size_t)(g * 32 + rowq0 + q) * 1024 + loff + hcol];
      hst[q] = h;
      store2h<FAST>(&hb[16384 + (rowq0 + q) * 512 + hcol], (_Float16)h);  // prefill parity-1
    }
    asm volatile("s_waitcnt vmcnt(0)" ::: "memory");
  }
  group_barrier(barp, 32u * (++phase), tid);

  const f16x8* Wb0 = (const f16x8*)Wlds;                 // Wh0 frags (LDS)
  const f16x8* Wb1 = (const f16x8*)(Wlds + 24576);       // Wi1 frags (LDS)
  const f16x8* Wb2 = (const f16x8*)(Wlds + 2 * 24576);   // Wh1 frags (LDS)
  const f16x8* WbX = (const f16x8*)(wt + (size_t)(3 * 32 + cid) * 24576);  // Wi0 frags (L2)

  for (int s = 0; s <= LSEQ; ++s) {
    const int pr = (s + 1) & 1;  // parity of state[s-1]
    const int pw = s & 1;        // parity of state[s] / state[s-2]
    f32x4 a0 = {0.f, 0.f, 0.f, 0.f}, a1 = {0.f, 0.f, 0.f, 0.f}, a2 = {0.f, 0.f, 0.f, 0.f};

    if (role == 0 && s < LSEQ) {            // gh0 = h0[s-1] @ Wh0
      const _Float16* Ap = h0buf + pr * 16384 + (mhalf * 16 + l16) * 512 + 8 * lhi;
      f16x8 afr[16];
#pragma unroll
      for (int kc = 0; kc < 16; ++kc) afr[kc] = __builtin_bit_cast(f16x8, load16h<FAST>(Ap + kc * 32));
      asm volatile("s_waitcnt vmcnt(0)" ::: "memory");
      __builtin_amdgcn_sched_barrier(0);
#pragma unroll
      for (int kc = 0; kc < 16; ++kc) {
        a0 = __builtin_amdgcn_mfma_f32_16x16x32_f16(afr[kc], Wb0[(kc * 3 + 0) * 64 + lane], a0, 0, 0, 0);
        a1 = __builtin_amdgcn_mfma_f32_16x16x32_f16(afr[kc], Wb0[(kc * 3 + 1) * 64 + lane], a1, 0, 0, 0);
        a2 = __builtin_amdgcn_mfma_f32_16x16x32_f16(afr[kc], Wb0[(kc * 3 + 2) * 64 + lane], a2, 0, 0, 0);
      }
#pragma unroll
      for (int q = 0; q < 4; ++q) {
        GH[(0 * 32 + rowq0 + q) * 16 + l16] = a0[q];
        GH[(1 * 32 + rowq0 + q) * 16 + l16] = a1[q];
        GH[(2 * 32 + rowq0 + q) * 16 + l16] = a2[q];
      }
    } else if (role == 3 && s >= 1) {       // gh1 = h1[s-2] @ Wh1
      const _Float16* Ap = h1buf + pw * 16384 + (mhalf * 16 + l16) * 512 + 8 * lhi;
      f16x8 afr[16];
#pragma unroll
      for (int kc = 0; kc < 16; ++kc) afr[kc] = __builtin_bit_cast(f16x8, load16h<FAST>(Ap + kc * 32));
      asm volatile("s_waitcnt vmcnt(0)" ::: "memory");
      __builtin_amdgcn_sched_barrier(0);
#pragma unroll
      for (int kc = 0; kc < 16; ++kc) {
        a0 = __builtin_amdgcn_mfma_f32_16x16x32_f16(afr[kc], Wb2[(kc * 3 + 0) * 64 + lane], a0, 0, 0, 0);
        a1 = __builtin_amdgcn_mfma_f32_16x16x32_f16(afr[kc], Wb2[(kc * 3 + 1) * 64 + lane], a1, 0, 0, 0);
        a2 = __builtin_amdgcn_mfma_f32_16x16x32_f16(afr[kc], Wb2[(kc * 3 + 2) * 64 + lane], a2, 0, 0, 0);
      }
#pragma unroll
      for (int q = 0; q < 4; ++q) {
        GH[((3 + 0) * 32 + rowq0 + q) * 16 + l16] = a0[q];
        GH[((3 + 1) * 32 + rowq0 + q) * 16 + l16] = a1[q];
        GH[((3 + 2) * 32 + rowq0 + q) * 16 + l16] = a2[q];
      }
    } else if (role == 1 && s < LSEQ) {     // gi0 = x[s] @ Wi0
      const float* xp = x + ((size_t)s * 256 + g * 32 + mhalf * 16 + l16) * 512 + 8 * lhi;
#pragma unroll
      for (int kc = 0; kc < 16; ++kc) {
        f32x4 xa = *(const f32x4*)(xp + kc * 32);
        f32x4 xb = *(const f32x4*)(xp + kc * 32 + 4);
        f16x8 a;
        a[0] = (_Float16)xa[0]; a[1] = (_Float16)xa[1]; a[2] = (_Float16)xa[2]; a[3] = (_Float16)xa[3];
        a[4] = (_Float16)xb[0]; a[5] = (_Float16)xb[1]; a[6] = (_Float16)xb[2]; a[7] = (_Float16)xb[3];
        a0 = __builtin_amdgcn_mfma_f32_16x16x32_f16(a, WbX[(kc * 3 + 0) * 64 + lane], a0, 0, 0, 0);
        a1 = __builtin_amdgcn_mfma_f32_16x16x32_f16(a, WbX[(kc * 3 + 1) * 64 + lane], a1, 0, 0, 0);
        a2 = __builtin_amdgcn_mfma_f32_16x16x32_f16(a, WbX[(kc * 3 + 2) * 64 + lane], a2, 0, 0, 0);
      }
    } else if (role == 2 && s >= 1) {       // gi1 = h0[s-1] @ Wi1
      const _Float16* Ap = h0buf + pr * 16384 + (mhalf * 16 + l16) * 512 + 8 * lhi;
      f16x8 afr[16];
#pragma unroll
      for (int kc = 0; kc < 16; ++kc) afr[kc] = __builtin_bit_cast(f16x8, load16h<FAST>(Ap + kc * 32));
      asm volatile("s_waitcnt vmcnt(0)" ::: "memory");
      __builtin_amdgcn_sched_barrier(0);
#pragma unroll
      for (int kc = 0; kc < 16; ++kc) {
        a0 = __builtin_amdgcn_mfma_f32_16x16x32_f16(afr[kc], Wb1[(kc * 3 + 0) * 64 + lane], a0, 0, 0, 0);
        a1 = __builtin_amdgcn_mfma_f32_16x16x32_f16(afr[kc], Wb1[(kc * 3 + 1) * 64 + lane], a1, 0, 0, 0);
        a2 = __builtin_amdgcn_mfma_f32_16x16x32_f16(afr[kc], Wb1[(kc * 3 + 2) * 64 + lane], a2, 0, 0, 0);
      }
    }
    __syncthreads();  // gh accs visible in LDS

    if (role == 1 && s < LSEQ) {            // layer-0 epilogue -> h0[s]
#pragma unroll
      for (int q = 0; q < 4; ++q) {
        const int row = rowq0 + q;
        float r = sig_(a0[q] + GH[(0 * 32 + row) * 16 + l16] + bR);
        float z = sig_(a1[q] + GH[(1 * 32 + row) * 16 + l16] + bZ);
        float n = tanh_(a2[q] + r * (GH[(2 * 32 + row) * 16 + l16] + bN));
        float h = (1.0f - z) * n + z * hst[q];
        hst[q] = h;
        store2h<FAST>(&h0buf[pw * 16384 + row * 512 + hcol], (_Float16)h);
        if (s == LSEQ - 1) out[(size_t)(g * 32 + row) * 1024 + hcol] = h;  // carry h0
      }
      asm volatile("s_waitcnt vmcnt(0)" ::: "memory");
    } else if (role == 2 && s >= 1) {       // layer-1 epilogue -> h1[s-1]
#pragma unroll
      for (int q = 0; q < 4; ++q) {
        const int row = rowq0 + q;
        float r = sig_(a0[q] + GH[((3 + 0) * 32 + row) * 16 + l16] + bR);
        float z = sig_(a1[q] + GH[((3 + 1) * 32 + row) * 16 + l16] + bZ);
        float n = tanh_(a2[q] + r * (GH[((3 + 2) * 32 + row) * 16 + l16] + bN));
        float h = (1.0f - z) * n + z * hst[q];
        hst[q] = h;
        store2h<FAST>(&h1buf[pr * 16384 + row * 512 + hcol], (_Float16)h);
        out[(size_t)262144 + ((size_t)(s - 1) * 256 + g * 32 + row) * 512 + hcol] = h;  // y[s-1]
        if (s == LSEQ) out[(size_t)(g * 32 + row) * 1024 + 512 + hcol] = h;             // carry h1
      }
      asm volatile("s_waitcnt vmcnt(0)" ::: "memory");
    }
    group_barrier(barp, 32u * (++phase), tid);
  }
}

__global__ void __launch_bounds__(512, 2)
gru_kernel(const float* __restrict__ carry, const float* __restrict__ x,
           const float* __restrict__ bh0, const float* __restrict__ bh1,
           float* __restrict__ out, char* __restrict__ ws) {
  extern __shared__ char smem[];
  _Float16* Wlds = (_Float16*)smem;     // [3][16][3][64][8] fragments: Wh0,Wi1,Wh1 slices (147456 B)
  float* GH = (float*)(smem + 147456);  // [2 layer][3 nt][32 row][16 col] acc exchange (12288 B)
  __shared__ int sh_g, sh_cid, sh_fast;

  const int tid = threadIdx.x;

  // --- deadlock-proof group discovery (one-time, IF$-scope) ---
  // g = physical XCC, cid = arrival rank. A global 256-block barrier (used
  // twice) verifies every XCC group has exactly 32 members; otherwise ALL
  // blocks fall back to bid-grouping + IF$ h-exchange (R2 semantics).
  if (tid == 0) {
    unsigned int xcc;
    asm volatile("s_getreg_b32 %0, hwreg(HW_REG_XCC_ID)" : "=s"(xcc));
    xcc &= 7u;
    unsigned int* rk = (unsigned int*)(ws + RANK_OFF) + xcc * 64;
    unsigned int* gb = (unsigned int*)(ws + GBAR_OFF);
    unsigned int* bd = (unsigned int*)(ws + BAD_OFF);
    unsigned int cid_raw = __hip_atomic_fetch_add(rk, 1u, __ATOMIC_RELAXED, __HIP_MEMORY_SCOPE_AGENT);
    asm volatile("s_waitcnt vmcnt(0)" ::: "memory");  // rank add globally visible
    __hip_atomic_fetch_add(gb, 1u, __ATOMIC_RELAXED, __HIP_MEMORY_SCOPE_AGENT);
    while (__hip_atomic_load(gb, __ATOMIC_RELAXED, __HIP_MEMORY_SCOPE_AGENT) < 256u) {}
    unsigned int cnt = __hip_atomic_load(rk, __ATOMIC_RELAXED, __HIP_MEMORY_SCOPE_AGENT);
    if (cnt != 32u || cid_raw >= 32u)
      __hip_atomic_fetch_add(bd, 1u, __ATOMIC_RELAXED, __HIP_MEMORY_SCOPE_AGENT);
    asm volatile("s_waitcnt vmcnt(0)" ::: "memory");  // bad flag visible before barrier 2
    __hip_atomic_fetch_add(gb, 1u, __ATOMIC_RELAXED, __HIP_MEMORY_SCOPE_AGENT);
    while (__hip_atomic_load(gb, __ATOMIC_RELAXED, __HIP_MEMORY_SCOPE_AGENT) < 512u) {}
    unsigned int badv = __hip_atomic_load(bd, __ATOMIC_RELAXED, __HIP_MEMORY_SCOPE_AGENT);
    sh_fast = (badv == 0u);
    sh_g    = (badv == 0u) ? (int)xcc     : (int)(blockIdx.x & 7);
    sh_cid  = (badv == 0u) ? (int)cid_raw : (int)(blockIdx.x >> 3);
  }
  __syncthreads();
  const int g = sh_g, cid = sh_cid;

  // Stage this CU's recurrent-weight fragments into LDS (straight vector copy).
  _Float16* wt = (_Float16*)(ws + WT_OFF);
  for (int w = 0; w < 3; ++w) {
    const f16x8* s8 = (const f16x8*)(wt + (size_t)(w * 32 + cid) * 24576);
    f16x8* d8 = (f16x8*)(Wlds + w * 24576);
    for (int i = tid; i < 3072; i += 512) d8[i] = s8[i];
  }

  if (sh_fast) run_scan<true>(g, cid, carry, x, bh0, bh1, out, ws, Wlds, GH);
  else         run_scan<false>(g, cid, carry, x, bh0, bh1, out, ws, Wlds, GH);
}

extern "C" void kernel_launch(void* const* d_in, const int* in_sizes, int n_in,
                              void* d_out, int out_size, void* d_ws, size_t ws_size,
                              hipStream_t stream) {
  const float* carry = (const float*)d_in[0];
  const float* x     = (const float*)d_in[1];
  const float* Wi0   = (const float*)d_in[2];
  const float* Wh0   = (const float*)d_in[3];
  const float* bh0   = (const float*)d_in[4];
  const float* Wi1   = (const float*)d_in[5];
  const float* Wh1   = (const float*)d_in[6];
  const float* bh1   = (const float*)d_in[7];
  float* out = (float*)d_out;
  char* ws = (char*)d_ws;

  prep_kernel<<<2048, 256, 0, stream>>>(Wh0, Wi1, Wh1, Wi0, ws);

  (void)hipFuncSetAttribute(reinterpret_cast<const void*>(gru_kernel),
                            hipFuncAttributeMaxDynamicSharedMemorySize, 159744);

  void* args[] = {(void*)&carry, (void*)&x, (void*)&bh0, (void*)&bh1, (void*)&out, (void*)&ws};
  (void)hipLaunchCooperativeKernel(reinterpret_cast<void*>(gru_kernel),
                                   dim3(256), dim3(512), args, 159744, stream);
}